// Round 4
// baseline (177.611 us; speedup 1.0000x reference)
//
#include <hip/hip_runtime.h>

// GNN encoder, B=256, N=32, F=256, fully-connected edges, 2 passes.
// bf16 MFMA 16x16x32, fp32 accum. Weights pre-swizzled into LDS-image layout.
// edge_fused v3: persistent batch-per-block, w_e2 held in registers (128 VGPR),
// A-only LDS double buffer, fully unrolled K loop.

typedef short bf16x8 __attribute__((ext_vector_type(8)));
typedef float f32x4 __attribute__((ext_vector_type(4)));
typedef unsigned short ushort_t;

__device__ __forceinline__ unsigned short f2bf(float f) {
    unsigned u = __float_as_uint(f);
    u += 0x7fff + ((u >> 16) & 1);   // RNE
    return (unsigned short)(u >> 16);
}
__device__ __forceinline__ unsigned cvt_pk_bf16(float lo, float hi) {
    unsigned r;
    asm volatile("v_cvt_pk_bf16_f32 %0, %1, %2" : "=v"(r) : "v"(lo), "v"(hi));
    return r;
}
__device__ __forceinline__ void gload16(const void* g, void* l) {
    __builtin_amdgcn_global_load_lds(
        (const __attribute__((address_space(1))) void*)g,
        (__attribute__((address_space(3))) void*)l, 16, 0, 0);
}

// ---------------------------------------------------------------------------
// Weight prep: logical Wt[n][k] -> swizzled LDS image:
// idx = kb*8192 + n*32 + (kc ^ ((n>>1)&3))*8 + (k&7), kb = k>>5, kc = (k>>3)&3.
__global__ __launch_bounds__(256) void prep_weights(
    const float* __restrict__ w_in1, const float* __restrict__ w_in2,
    const float* __restrict__ w_e1,  const float* __restrict__ w_e2,
    const float* __restrict__ w_n1,  const float* __restrict__ w_n2,
    ushort_t* __restrict__ dst)
{
    __shared__ ushort_t tile[32][264];
    const int wid = blockIdx.x >> 3;   // 0..6
    const int kb  = blockIdx.x & 7;
    const float* src;
    switch (wid) {
        case 0: src = w_in1; break;
        case 1: src = w_in2; break;
        case 2: src = w_e1; break;              // top half (send side)
        case 3: src = w_e1 + 65536; break;      // bottom half (recv side)
        case 4: src = w_e2; break;
        case 5: src = w_n1; break;
        default: src = w_n2; break;
    }
    const int t = threadIdx.x;
#pragma unroll
    for (int k0 = 0; k0 < 32; k0++)
        tile[k0][t] = f2bf(src[(size_t)(kb * 32 + k0) * 256 + t]);  // coalesced
    __syncthreads();
    ushort_t* base = dst + wid * 65536 + kb * 8192 + t * 32;
    const int sw = (t >> 1) & 3;
#pragma unroll
    for (int kc = 0; kc < 4; kc++) {
        union { uint4 q; ushort_t u[8]; } w;
#pragma unroll
        for (int ko = 0; ko < 8; ko++) w.u[ko] = tile[kc * 8 + ko][t];
        *(uint4*)&base[(kc ^ sw) * 8] = w.q;
    }
}

// x fp32 -> bf16
__global__ __launch_bounds__(256) void conv_x(
    const float* __restrict__ x, ushort_t* __restrict__ xb, int n8)
{
    int i = blockIdx.x * 256 + threadIdx.x;
    if (i >= n8) return;
    const float4* p = (const float4*)x + (size_t)i * 2;
    float4 a = p[0], b = p[1];
    ushort4 o0 = make_ushort4(f2bf(a.x), f2bf(a.y), f2bf(a.z), f2bf(a.w));
    ushort4 o1 = make_ushort4(f2bf(b.x), f2bf(b.y), f2bf(b.z), f2bf(b.w));
    ((ushort4*)xb)[(size_t)i * 2]     = o0;
    ((ushort4*)xb)[(size_t)i * 2 + 1] = o1;
}

// ---------------------------------------------------------------------------
// Direct GEMM. Tile 64x64, 4 waves (2x2), gload_lds staging, 1-barrier dbuf.
// split: blockIdx.y >= split selects second weight image (WB+65536), null bias,
// output cols offset by 256 (merged U'/V dispatch).
// EPI: 0 raw f32, 1 bias f32, 2 bias+relu bf16, 3 bias+relu f32
template <int EPI>
__global__ __launch_bounds__(256) void gemm64(
    const ushort_t* __restrict__ A, const ushort_t* __restrict__ WB,
    const float* __restrict__ bias, void* __restrict__ out, int ldc, int split)
{
    __shared__ ushort_t As[2][2048];
    __shared__ ushort_t Bs[2][2048];

    const int mb = (blockIdx.x & 7) * 16 + (blockIdx.x >> 3);  // XCD swizzle
    const int m0 = mb * 64;
    const int ny = blockIdx.y;
    int nloc; const ushort_t* wb; const float* bp; int nout;
    if (ny >= split) { nloc = (ny - split) * 64; wb = WB + 65536; bp = nullptr; nout = 256 + nloc; }
    else             { nloc = ny * 64;           wb = WB;         bp = bias;    nout = nloc; }

    const int t = threadIdx.x;
    const int lane = t & 63;
    const int w = t >> 6;
    const int wm = w >> 1, wn = w & 1;
    const int lr = lane & 15, lg = lane >> 4;

    const int arow = w * 16 + (lane >> 2);
    const int ac = (lane & 3) ^ ((arow >> 1) & 3);
    const ushort_t* asrc = A + (size_t)(m0 + arow) * 256 + ac * 8;
    const ushort_t* bsrc = wb + nloc * 32 + w * 512 + lane * 8;

    int aoff[2], boff[2];
#pragma unroll
    for (int f = 0; f < 2; f++) {
        int r = wm * 32 + f * 16 + lr;
        aoff[f] = r * 32 + ((lg ^ ((r >> 1) & 3)) * 8);
        int rb = wn * 32 + f * 16 + lr;
        boff[f] = rb * 32 + ((lg ^ ((rb >> 1) & 3)) * 8);
    }

    f32x4 acc[2][2] = {};

    gload16(asrc, &As[0][w * 512]);
    gload16(bsrc, &Bs[0][w * 512]);

    for (int kb = 1; kb < 8; kb++) {
        __syncthreads();
        gload16(asrc + kb * 32,   &As[kb & 1][w * 512]);
        gload16(bsrc + kb * 8192, &Bs[kb & 1][w * 512]);
        const int cur = (kb - 1) & 1;
        bf16x8 a0 = *(const bf16x8*)&As[cur][aoff[0]];
        bf16x8 a1 = *(const bf16x8*)&As[cur][aoff[1]];
        bf16x8 b0 = *(const bf16x8*)&Bs[cur][boff[0]];
        bf16x8 b1 = *(const bf16x8*)&Bs[cur][boff[1]];
        acc[0][0] = __builtin_amdgcn_mfma_f32_16x16x32_bf16(a0, b0, acc[0][0], 0, 0, 0);
        acc[0][1] = __builtin_amdgcn_mfma_f32_16x16x32_bf16(a0, b1, acc[0][1], 0, 0, 0);
        acc[1][0] = __builtin_amdgcn_mfma_f32_16x16x32_bf16(a1, b0, acc[1][0], 0, 0, 0);
        acc[1][1] = __builtin_amdgcn_mfma_f32_16x16x32_bf16(a1, b1, acc[1][1], 0, 0, 0);
    }
    __syncthreads();
    {
        bf16x8 a0 = *(const bf16x8*)&As[1][aoff[0]];
        bf16x8 a1 = *(const bf16x8*)&As[1][aoff[1]];
        bf16x8 b0 = *(const bf16x8*)&Bs[1][boff[0]];
        bf16x8 b1 = *(const bf16x8*)&Bs[1][boff[1]];
        acc[0][0] = __builtin_amdgcn_mfma_f32_16x16x32_bf16(a0, b0, acc[0][0], 0, 0, 0);
        acc[0][1] = __builtin_amdgcn_mfma_f32_16x16x32_bf16(a0, b1, acc[0][1], 0, 0, 0);
        acc[1][0] = __builtin_amdgcn_mfma_f32_16x16x32_bf16(a1, b0, acc[1][0], 0, 0, 0);
        acc[1][1] = __builtin_amdgcn_mfma_f32_16x16x32_bf16(a1, b1, acc[1][1], 0, 0, 0);
    }

#pragma unroll
    for (int fm = 0; fm < 2; fm++)
#pragma unroll
        for (int fn = 0; fn < 2; fn++) {
            const int cl = wn * 32 + fn * 16 + lr;     // col within 64-tile
            float bv = 0.f;
            if constexpr (EPI != 0) { if (bp) bv = bp[nloc + cl]; }
#pragma unroll
            for (int r = 0; r < 4; r++) {
                const int row = m0 + wm * 32 + fm * 16 + lg * 4 + r;
                float v = acc[fm][fn][r] + bv;
                if constexpr (EPI >= 2) v = fmaxf(v, 0.f);
                if constexpr (EPI == 2)
                    ((ushort_t*)out)[(size_t)row * ldc + nout + cl] = f2bf(v);
                else
                    ((float*)out)[(size_t)row * ldc + nout + cl] = v;
            }
        }
}

// ---------------------------------------------------------------------------
// Fused edge layer-2 + scatter-mean, v3: persistent batch-per-block.
// Grid 256 blocks x 512 thr (8 waves, 2m x 4n). Block = one batch (32 recv =
// 8 groups of 4). w_e2 held in registers (32 bf16x8 frags/wave, all K).
// Per group: 128 virtual rows (4 recv x 32 slots, slot 31 dummy) x N=256,
// A = relu(U'[send]+V[recv]) built on the fly into LDS dbuf (only LDS user).
__global__ __launch_bounds__(512, 2) void edge_fused(
    const float* __restrict__ UV,       // [8192][512] f32: U'(+b_e1) | V
    const ushort_t* __restrict__ WBsw,  // swizzled w_e2 image
    const float* __restrict__ b2,
    ushort_t* __restrict__ agg)         // [8192][256] bf16
{
    __shared__ ushort_t As[2][4096];    // 128 rows x 32 k

    const int bb = (blockIdx.x & 7) * 32 + (blockIdx.x >> 3);  // batch (256 blocks)
    const int t = threadIdx.x;
    const int lane = t & 63;
    const int w = t >> 6;
    const int wm = w >> 2, wn = w & 3;
    const int lr = lane & 15, lg = lane >> 4;

    // A-build constants
    const int arow = t >> 2;            // 0..127
    const int ac = t & 3;
    const int jr = arow >> 5;           // receiver within group
    const int s = arow & 31;            // slot
    const int awoff = arow * 32 + ((ac ^ ((arow >> 1) & 3)) * 8);

    int aoff[4];
#pragma unroll
    for (int f = 0; f < 4; f++) {
        int r = wm * 64 + f * 16 + lr;
        aoff[f] = r * 32 + ((lg ^ ((r >> 1) & 3)) * 8);
    }

    // w_e2 -> registers: frag[kb][fn] = W2t[wn*64+fn*16+lr][kb*32+lg*8..+8]
    bf16x8 breg[8][4];
#pragma unroll
    for (int kb = 0; kb < 8; kb++)
#pragma unroll
        for (int fn = 0; fn < 4; fn++) {
            const int n = wn * 64 + fn * 16 + lr;
            breg[kb][fn] = *(const bf16x8*)&WBsw[kb * 8192 + n * 32 + ((lg ^ ((n >> 1) & 3)) * 8)];
        }
    float bv[4];
#pragma unroll
    for (int fn = 0; fn < 4; fn++) bv[fn] = b2[wn * 64 + fn * 16 + lr];

    for (int g = 0; g < 8; g++) {
        const int j = g * 4 + jr;
        const int si = (s == 31) ? j : (s + (s >= j ? 1 : 0));
        const float* up = UV + (size_t)(bb * 32 + si) * 512 + ac * 8;
        const float* vp = UV + (size_t)(bb * 32 + j) * 512 + 256 + ac * 8;

        f32x4 acc[4][4] = {};

        // build k-tile 0
        {
            float4 u0 = ((const float4*)up)[0], u1 = ((const float4*)up)[1];
            float4 v0 = ((const float4*)vp)[0], v1 = ((const float4*)vp)[1];
            uint4 q;
            q.x = cvt_pk_bf16(fmaxf(u0.x + v0.x, 0.f), fmaxf(u0.y + v0.y, 0.f));
            q.y = cvt_pk_bf16(fmaxf(u0.z + v0.z, 0.f), fmaxf(u0.w + v0.w, 0.f));
            q.z = cvt_pk_bf16(fmaxf(u1.x + v1.x, 0.f), fmaxf(u1.y + v1.y, 0.f));
            q.w = cvt_pk_bf16(fmaxf(u1.z + v1.z, 0.f), fmaxf(u1.w + v1.w, 0.f));
            *(uint4*)&As[0][awoff] = q;
        }

#pragma unroll
        for (int kb = 0; kb < 8; kb++) {
            const int cur = kb & 1;
            __syncthreads();                       // As[cur] ready
            float4 u0, u1, v0, v1;
            if (kb < 7) {                          // issue next loads post-barrier
                const float* upn = up + (kb + 1) * 32;
                const float* vpn = vp + (kb + 1) * 32;
                u0 = ((const float4*)upn)[0]; u1 = ((const float4*)upn)[1];
                v0 = ((const float4*)vpn)[0]; v1 = ((const float4*)vpn)[1];
            }
            bf16x8 af[4];
#pragma unroll
            for (int f = 0; f < 4; f++) af[f] = *(const bf16x8*)&As[cur][aoff[f]];
#pragma unroll
            for (int fm = 0; fm < 4; fm++)
#pragma unroll
                for (int fn = 0; fn < 4; fn++)
                    acc[fm][fn] = __builtin_amdgcn_mfma_f32_16x16x32_bf16(
                        af[fm], breg[kb][fn], acc[fm][fn], 0, 0, 0);
            if (kb < 7) {                          // build next tile (loads drained here)
                uint4 q;
                q.x = cvt_pk_bf16(fmaxf(u0.x + v0.x, 0.f), fmaxf(u0.y + v0.y, 0.f));
                q.y = cvt_pk_bf16(fmaxf(u0.z + v0.z, 0.f), fmaxf(u0.w + v0.w, 0.f));
                q.z = cvt_pk_bf16(fmaxf(u1.x + v1.x, 0.f), fmaxf(u1.y + v1.y, 0.f));
                q.w = cvt_pk_bf16(fmaxf(u1.z + v1.z, 0.f), fmaxf(u1.w + v1.w, 0.f));
                *(uint4*)&As[cur ^ 1][awoff] = q;
            }
        }

        // Epilogue: bias+relu, row-sum over 31 real slots per receiver, /31.
#pragma unroll
        for (int fn = 0; fn < 4; fn++) {
            const int col = wn * 64 + fn * 16 + lr;
#pragma unroll
            for (int h = 0; h < 2; h++) {
                float sum = 0.f;
#pragma unroll
                for (int q = 0; q < 2; q++) {
                    const int fm = 2 * h + q;
#pragma unroll
                    for (int r = 0; r < 4; r++) {
                        float v = acc[fm][fn][r] + bv[fn];
                        v = fmaxf(v, 0.f);
                        if (!(q == 1 && lg == 3 && r == 3)) sum += v;  // skip slot 31
                    }
                }
                sum += __shfl_xor(sum, 16);
                sum += __shfl_xor(sum, 32);
                if (lane < 16) {
                    const int node = bb * 32 + g * 4 + 2 * wm + h;
                    agg[(size_t)node * 256 + col] = f2bf(sum * (1.0f / 31.0f));
                }
            }
        }
    }
}

// ---------------------------------------------------------------------------
extern "C" void kernel_launch(void* const* d_in, const int* in_sizes, int n_in,
                              void* d_out, int out_size, void* d_ws, size_t ws_size,
                              hipStream_t stream)
{
    const float* x     = (const float*)d_in[0];
    const float* w_in1 = (const float*)d_in[3];
    const float* b_in1 = (const float*)d_in[4];
    const float* w_in2 = (const float*)d_in[5];
    const float* b_in2 = (const float*)d_in[6];
    const float* w_e1  = (const float*)d_in[7];
    const float* b_e1  = (const float*)d_in[8];
    const float* w_e2  = (const float*)d_in[9];
    const float* b_e2  = (const float*)d_in[10];
    const float* w_n1  = (const float*)d_in[11];
    const float* b_n1  = (const float*)d_in[12];
    const float* w_n2  = (const float*)d_in[13];
    const float* b_n2  = (const float*)d_in[14];

    char* ws = (char*)d_ws;
    size_t off = 0;
    auto alloc = [&](size_t n) { char* p = ws + off; off += (n + 255) & ~(size_t)255; return p; };

    ushort_t* wt  = (ushort_t*)alloc(7 * 65536 * sizeof(ushort_t));
    ushort_t* xb  = (ushort_t*)alloc(8192 * 256 * 2);
    ushort_t* h   = (ushort_t*)alloc(8192 * 256 * 2);
    ushort_t* t1  = (ushort_t*)alloc(8192 * 256 * 2);
    float*    UVf = (float*)   alloc(8192 * 512 * 4);
    ushort_t* ag  = (ushort_t*)alloc(8192 * 256 * 2);
    (void)ws_size; (void)in_sizes; (void)n_in; (void)out_size;

    prep_weights<<<56, 256, 0, stream>>>(w_in1, w_in2, w_e1, w_e2, w_n1, w_n2, wt);
    conv_x<<<1024, 256, 0, stream>>>(x, xb, 262144);

    dim3 gs(128, 4);
    gemm64<2><<<gs, 256, 0, stream>>>(xb, wt + 0 * 65536, b_in1, t1, 256, 99);
    gemm64<2><<<gs, 256, 0, stream>>>(t1, wt + 1 * 65536, b_in2, h, 256, 99);

    for (int p = 0; p < 2; p++) {
        // U' = h@We1_top + b_e1, V = h@We1_bot — one dispatch, split at y=4
        dim3 guv(128, 8);
        gemm64<1><<<guv, 256, 0, stream>>>(h, wt + 2 * 65536, b_e1, UVf, 512, 4);
        edge_fused<<<256, 512, 0, stream>>>(UVf, wt + 4 * 65536, b_e2, ag);
        gemm64<2><<<gs, 256, 0, stream>>>(ag, wt + 5 * 65536, b_n1, t1, 256, 99);
        if (p == 0)
            gemm64<2><<<gs, 256, 0, stream>>>(t1, wt + 6 * 65536, b_n2, h, 256, 99);
        else
            gemm64<3><<<gs, 256, 0, stream>>>(t1, wt + 6 * 65536, b_n2, (float*)d_out, 256, 99);
    }
}

// Round 5
// 167.112 us; speedup vs baseline: 1.0628x; 1.0628x over previous
//
#include <hip/hip_runtime.h>

// GNN encoder, B=256, N=32, F=256, fully-connected edges, 2 passes.
// bf16 MFMA 16x16x32, fp32 accum.
// edge_fused v5: per-half-batch blocks, w_e2 K-resident in registers,
// UV in bf16, sender-major A-build (u-reuse), A-only LDS dbuf.

typedef short bf16x8 __attribute__((ext_vector_type(8)));
typedef float f32x4 __attribute__((ext_vector_type(4)));
typedef unsigned short ushort_t;

__device__ __forceinline__ unsigned short f2bf(float f) {
    unsigned u = __float_as_uint(f);
    u += 0x7fff + ((u >> 16) & 1);   // RNE
    return (unsigned short)(u >> 16);
}
__device__ __forceinline__ float lo16f(unsigned w) { return __uint_as_float(w << 16); }
__device__ __forceinline__ float hi16f(unsigned w) { return __uint_as_float(w & 0xffff0000u); }
__device__ __forceinline__ unsigned cvt_pk_bf16(float lo, float hi) {
    unsigned r;
    asm volatile("v_cvt_pk_bf16_f32 %0, %1, %2" : "=v"(r) : "v"(lo), "v"(hi));
    return r;
}
__device__ __forceinline__ void gload16(const void* g, void* l) {
    __builtin_amdgcn_global_load_lds(
        (const __attribute__((address_space(1))) void*)g,
        (__attribute__((address_space(3))) void*)l, 16, 0, 0);
}

// ---------------------------------------------------------------------------
// Weight prep: logical Wt[n][k] -> swizzled LDS image:
// idx = kb*8192 + n*32 + (kc ^ ((n>>1)&3))*8 + (k&7), kb = k>>5, kc = (k>>3)&3.
__global__ __launch_bounds__(256) void prep_weights(
    const float* __restrict__ w_in1, const float* __restrict__ w_in2,
    const float* __restrict__ w_e1,  const float* __restrict__ w_e2,
    const float* __restrict__ w_n1,  const float* __restrict__ w_n2,
    ushort_t* __restrict__ dst)
{
    __shared__ ushort_t tile[32][264];
    const int wid = blockIdx.x >> 3;   // 0..6
    const int kb  = blockIdx.x & 7;
    const float* src;
    switch (wid) {
        case 0: src = w_in1; break;
        case 1: src = w_in2; break;
        case 2: src = w_e1; break;              // top half (send side)
        case 3: src = w_e1 + 65536; break;      // bottom half (recv side)
        case 4: src = w_e2; break;
        case 5: src = w_n1; break;
        default: src = w_n2; break;
    }
    const int t = threadIdx.x;
#pragma unroll
    for (int k0 = 0; k0 < 32; k0++)
        tile[k0][t] = f2bf(src[(size_t)(kb * 32 + k0) * 256 + t]);  // coalesced
    __syncthreads();
    ushort_t* base = dst + wid * 65536 + kb * 8192 + t * 32;
    const int sw = (t >> 1) & 3;
#pragma unroll
    for (int kc = 0; kc < 4; kc++) {
        union { uint4 q; ushort_t u[8]; } w;
#pragma unroll
        for (int ko = 0; ko < 8; ko++) w.u[ko] = tile[kc * 8 + ko][t];
        *(uint4*)&base[(kc ^ sw) * 8] = w.q;
    }
}

// x fp32 -> bf16
__global__ __launch_bounds__(256) void conv_x(
    const float* __restrict__ x, ushort_t* __restrict__ xb, int n8)
{
    int i = blockIdx.x * 256 + threadIdx.x;
    if (i >= n8) return;
    const float4* p = (const float4*)x + (size_t)i * 2;
    float4 a = p[0], b = p[1];
    ushort4 o0 = make_ushort4(f2bf(a.x), f2bf(a.y), f2bf(a.z), f2bf(a.w));
    ushort4 o1 = make_ushort4(f2bf(b.x), f2bf(b.y), f2bf(b.z), f2bf(b.w));
    ((ushort4*)xb)[(size_t)i * 2]     = o0;
    ((ushort4*)xb)[(size_t)i * 2 + 1] = o1;
}

// ---------------------------------------------------------------------------
// Direct GEMM. Tile 64x64, 4 waves (2x2), gload_lds staging, 1-barrier dbuf.
// split: blockIdx.y >= split -> second weight image (WB+65536), null bias,
// output cols offset 256 (merged U'/V dispatch).
// EPI: 2 bias+relu bf16, 3 bias+relu f32, 4 bias(optional)+no-relu bf16
template <int EPI>
__global__ __launch_bounds__(256) void gemm64(
    const ushort_t* __restrict__ A, const ushort_t* __restrict__ WB,
    const float* __restrict__ bias, void* __restrict__ out, int ldc, int split)
{
    __shared__ ushort_t As[2][2048];
    __shared__ ushort_t Bs[2][2048];

    const int mb = (blockIdx.x & 7) * 16 + (blockIdx.x >> 3);  // XCD swizzle
    const int m0 = mb * 64;
    const int ny = blockIdx.y;
    int nloc; const ushort_t* wb; const float* bp; int nout;
    if (ny >= split) { nloc = (ny - split) * 64; wb = WB + 65536; bp = nullptr; nout = 256 + nloc; }
    else             { nloc = ny * 64;           wb = WB;         bp = bias;    nout = nloc; }

    const int t = threadIdx.x;
    const int lane = t & 63;
    const int w = t >> 6;
    const int wm = w >> 1, wn = w & 1;
    const int lr = lane & 15, lg = lane >> 4;

    const int arow = w * 16 + (lane >> 2);
    const int ac = (lane & 3) ^ ((arow >> 1) & 3);
    const ushort_t* asrc = A + (size_t)(m0 + arow) * 256 + ac * 8;
    const ushort_t* bsrc = wb + nloc * 32 + w * 512 + lane * 8;

    int aoff[2], boff[2];
#pragma unroll
    for (int f = 0; f < 2; f++) {
        int r = wm * 32 + f * 16 + lr;
        aoff[f] = r * 32 + ((lg ^ ((r >> 1) & 3)) * 8);
        int rb = wn * 32 + f * 16 + lr;
        boff[f] = rb * 32 + ((lg ^ ((rb >> 1) & 3)) * 8);
    }

    f32x4 acc[2][2] = {};

    gload16(asrc, &As[0][w * 512]);
    gload16(bsrc, &Bs[0][w * 512]);

    for (int kb = 1; kb < 8; kb++) {
        __syncthreads();
        gload16(asrc + kb * 32,   &As[kb & 1][w * 512]);
        gload16(bsrc + kb * 8192, &Bs[kb & 1][w * 512]);
        const int cur = (kb - 1) & 1;
        bf16x8 a0 = *(const bf16x8*)&As[cur][aoff[0]];
        bf16x8 a1 = *(const bf16x8*)&As[cur][aoff[1]];
        bf16x8 b0 = *(const bf16x8*)&Bs[cur][boff[0]];
        bf16x8 b1 = *(const bf16x8*)&Bs[cur][boff[1]];
        acc[0][0] = __builtin_amdgcn_mfma_f32_16x16x32_bf16(a0, b0, acc[0][0], 0, 0, 0);
        acc[0][1] = __builtin_amdgcn_mfma_f32_16x16x32_bf16(a0, b1, acc[0][1], 0, 0, 0);
        acc[1][0] = __builtin_amdgcn_mfma_f32_16x16x32_bf16(a1, b0, acc[1][0], 0, 0, 0);
        acc[1][1] = __builtin_amdgcn_mfma_f32_16x16x32_bf16(a1, b1, acc[1][1], 0, 0, 0);
    }
    __syncthreads();
    {
        bf16x8 a0 = *(const bf16x8*)&As[1][aoff[0]];
        bf16x8 a1 = *(const bf16x8*)&As[1][aoff[1]];
        bf16x8 b0 = *(const bf16x8*)&Bs[1][boff[0]];
        bf16x8 b1 = *(const bf16x8*)&Bs[1][boff[1]];
        acc[0][0] = __builtin_amdgcn_mfma_f32_16x16x32_bf16(a0, b0, acc[0][0], 0, 0, 0);
        acc[0][1] = __builtin_amdgcn_mfma_f32_16x16x32_bf16(a0, b1, acc[0][1], 0, 0, 0);
        acc[1][0] = __builtin_amdgcn_mfma_f32_16x16x32_bf16(a1, b0, acc[1][0], 0, 0, 0);
        acc[1][1] = __builtin_amdgcn_mfma_f32_16x16x32_bf16(a1, b1, acc[1][1], 0, 0, 0);
    }

#pragma unroll
    for (int fm = 0; fm < 2; fm++)
#pragma unroll
        for (int fn = 0; fn < 2; fn++) {
            const int cl = wn * 32 + fn * 16 + lr;
            float bv = 0.f;
            if (bp) bv = bp[nloc + cl];
#pragma unroll
            for (int r = 0; r < 4; r++) {
                const int row = m0 + wm * 32 + fm * 16 + lg * 4 + r;
                float v = acc[fm][fn][r] + bv;
                if constexpr (EPI == 2 || EPI == 3) v = fmaxf(v, 0.f);
                if constexpr (EPI == 3)
                    ((float*)out)[(size_t)row * ldc + nout + cl] = v;
                else
                    ((ushort_t*)out)[(size_t)row * ldc + nout + cl] = f2bf(v);
            }
        }
}

// ---------------------------------------------------------------------------
// Fused edge layer-2 + scatter-mean, v5.
// Grid 512 blocks x 512 thr (8 waves, 2m x 4n). Block = half batch (16 recv =
// 4 groups of 4 receivers). w_e2 K-resident in registers (breg[8][4]).
// Per group: 128 virtual rows (4 recv x 32 slots, slot31 dummy) x N=256.
// A = relu(U'[send]+V[recv]) from bf16 UV, built sender-major:
// thread = (si in 32, khc in 8, jh in 2) builds 2 rows x 4 k-elems.
__global__ __launch_bounds__(512, 2) void edge_fused(
    const ushort_t* __restrict__ UVb,   // [8192][512] bf16: U'(+b_e1) | V
    const ushort_t* __restrict__ WBsw,  // swizzled w_e2 image
    const float* __restrict__ b2,
    ushort_t* __restrict__ agg)         // [8192][256] bf16
{
    __shared__ ushort_t As[2][4096];    // 128 rows x 32 k, XOR-swizzled chunks

    const int logical = (blockIdx.x & 7) * 64 + (blockIdx.x >> 3);  // 512%8==0
    const int bb   = logical >> 1;      // batch
    const int half = logical & 1;       // which 16 receivers
    const int t = threadIdx.x;
    const int lane = t & 63;
    const int w = t >> 6;
    const int wm = w >> 2, wn = w & 3;  // 2m x 4n
    const int lr = lane & 15, lg = lane >> 4;

    // ---- sender-major build mapping: t = si*16 + khc*2 + jh
    const int si  = t >> 4;             // sender 0..31
    const int khc = (t >> 1) & 7;       // k half-chunk (4 elems)
    const int jh  = t & 1;              // receiver pair within group
    const int kc  = khc >> 1;           // 16B chunk
    const int kh  = khc & 1;            // half within chunk
    const ushort_t* upt = UVb + (size_t)(bb * 32 + si) * 512 + khc * 4;

    // group-dependent build state
    int awA = 0, awB = 0;
    const ushort_t* vApt = nullptr;
    const ushort_t* vBpt = nullptr;
    auto set_map = [&](int g) {
        const int jA = half * 16 + g * 4 + 2 * jh;
        const int jB = jA + 1;
        const int sA = (si == jA) ? 31 : si - (si > jA ? 1 : 0);
        const int sB = (si == jB) ? 31 : si - (si > jB ? 1 : 0);
        const int rowA = (2 * jh) * 32 + sA;
        const int rowB = (2 * jh + 1) * 32 + sB;
        awA = rowA * 32 + ((kc ^ ((rowA >> 1) & 3)) * 8) + kh * 4;
        awB = rowB * 32 + ((kc ^ ((rowB >> 1) & 3)) * 8) + kh * 4;
        vApt = UVb + (size_t)(bb * 32 + jA) * 512 + 256 + khc * 4;
        vBpt = UVb + (size_t)(bb * 32 + jB) * 512 + 256 + khc * 4;
    };
    set_map(0);

    // ---- MFMA-side constants
    int aoff[4];
#pragma unroll
    for (int f = 0; f < 4; f++) {
        int r = wm * 64 + f * 16 + lr;
        aoff[f] = r * 32 + ((lg ^ ((r >> 1) & 3)) * 8);
    }

    // w_e2 -> registers
    bf16x8 breg[8][4];
#pragma unroll
    for (int kb = 0; kb < 8; kb++)
#pragma unroll
        for (int fn = 0; fn < 4; fn++) {
            const int n = wn * 64 + fn * 16 + lr;
            breg[kb][fn] = *(const bf16x8*)&WBsw[kb * 8192 + n * 32 + ((lg ^ ((n >> 1) & 3)) * 8)];
        }
    float bv[4];
#pragma unroll
    for (int fn = 0; fn < 4; fn++) bv[fn] = b2[wn * 64 + fn * 16 + lr];

    // build 8 elems (2 rows x 4) from uint2 u, vA, vB into As[buf]
    auto build = [&](int buf, uint2 u, uint2 vA, uint2 vB) {
        float u0 = lo16f(u.x), u1 = hi16f(u.x), u2 = lo16f(u.y), u3 = hi16f(u.y);
        uint2 qA, qB;
        qA.x = cvt_pk_bf16(fmaxf(u0 + lo16f(vA.x), 0.f), fmaxf(u1 + hi16f(vA.x), 0.f));
        qA.y = cvt_pk_bf16(fmaxf(u2 + lo16f(vA.y), 0.f), fmaxf(u3 + hi16f(vA.y), 0.f));
        qB.x = cvt_pk_bf16(fmaxf(u0 + lo16f(vB.x), 0.f), fmaxf(u1 + hi16f(vB.x), 0.f));
        qB.y = cvt_pk_bf16(fmaxf(u2 + lo16f(vB.y), 0.f), fmaxf(u3 + hi16f(vB.y), 0.f));
        *(uint2*)&As[buf][awA] = qA;
        *(uint2*)&As[buf][awB] = qB;
    };

    // prologue: build tile (g=0, kb=0)
    {
        uint2 u  = *(const uint2*)upt;
        uint2 vA = *(const uint2*)vApt;
        uint2 vB = *(const uint2*)vBpt;
        build(0, u, vA, vB);
    }

    f32x4 acc[4][4] = {};

    for (int g = 0; g < 4; ++g) {
#pragma unroll
        for (int kb = 0; kb < 8; ++kb) {
            const int cur = kb & 1;
            __syncthreads();                      // As[cur] ready for all
            const bool hasnext = !(g == 3 && kb == 7);
            uint2 u, vA, vB;
            if (kb == 7) { if (g < 3) set_map(g + 1); }
            if (hasnext) {                        // issue loads for next tile
                const int kn = (kb == 7) ? 0 : (kb + 1);
                u  = *(const uint2*)(upt  + kn * 32);
                vA = *(const uint2*)(vApt + kn * 32);
                vB = *(const uint2*)(vBpt + kn * 32);
            }
            // MFMA on As[cur] (kb static -> breg static-indexed)
            bf16x8 af[4];
#pragma unroll
            for (int f = 0; f < 4; f++) af[f] = *(const bf16x8*)&As[cur][aoff[f]];
#pragma unroll
            for (int fm = 0; fm < 4; fm++)
#pragma unroll
                for (int fn = 0; fn < 4; fn++)
                    acc[fm][fn] = __builtin_amdgcn_mfma_f32_16x16x32_bf16(
                        af[fm], breg[kb][fn], acc[fm][fn], 0, 0, 0);
            if (hasnext) build(cur ^ 1, u, vA, vB);  // loads arrived under MFMA
        }

        // Epilogue for group g: bias+relu, sum 31 real slots, /31, write bf16.
#pragma unroll
        for (int fn = 0; fn < 4; fn++) {
            const int col = wn * 64 + fn * 16 + lr;
#pragma unroll
            for (int h = 0; h < 2; h++) {
                float sum = 0.f;
#pragma unroll
                for (int q = 0; q < 2; q++) {
                    const int fm = 2 * h + q;
#pragma unroll
                    for (int r = 0; r < 4; r++) {
                        float v = acc[fm][fn][r] + bv[fn];
                        v = fmaxf(v, 0.f);
                        if (!(q == 1 && lg == 3 && r == 3)) sum += v;  // slot 31
                    }
                }
                sum += __shfl_xor(sum, 16);
                sum += __shfl_xor(sum, 32);
                if (lane < 16) {
                    const int node = bb * 32 + half * 16 + g * 4 + 2 * wm + h;
                    agg[(size_t)node * 256 + col] = f2bf(sum * (1.0f / 31.0f));
                }
            }
        }
#pragma unroll
        for (int fm = 0; fm < 4; fm++)
#pragma unroll
            for (int fn = 0; fn < 4; fn++) acc[fm][fn] = (f32x4){0.f, 0.f, 0.f, 0.f};
    }
}

// ---------------------------------------------------------------------------
extern "C" void kernel_launch(void* const* d_in, const int* in_sizes, int n_in,
                              void* d_out, int out_size, void* d_ws, size_t ws_size,
                              hipStream_t stream)
{
    const float* x     = (const float*)d_in[0];
    const float* w_in1 = (const float*)d_in[3];
    const float* b_in1 = (const float*)d_in[4];
    const float* w_in2 = (const float*)d_in[5];
    const float* b_in2 = (const float*)d_in[6];
    const float* w_e1  = (const float*)d_in[7];
    const float* b_e1  = (const float*)d_in[8];
    const float* w_e2  = (const float*)d_in[9];
    const float* b_e2  = (const float*)d_in[10];
    const float* w_n1  = (const float*)d_in[11];
    const float* b_n1  = (const float*)d_in[12];
    const float* w_n2  = (const float*)d_in[13];
    const float* b_n2  = (const float*)d_in[14];

    char* ws = (char*)d_ws;
    size_t off = 0;
    auto alloc = [&](size_t n) { char* p = ws + off; off += (n + 255) & ~(size_t)255; return p; };

    ushort_t* wt  = (ushort_t*)alloc(7 * 65536 * sizeof(ushort_t));
    ushort_t* xb  = (ushort_t*)alloc(8192 * 256 * 2);
    ushort_t* h   = (ushort_t*)alloc(8192 * 256 * 2);
    ushort_t* t1  = (ushort_t*)alloc(8192 * 256 * 2);
    ushort_t* UVb = (ushort_t*)alloc(8192 * 512 * 2);
    ushort_t* ag  = (ushort_t*)alloc(8192 * 256 * 2);
    (void)ws_size; (void)in_sizes; (void)n_in; (void)out_size;

    prep_weights<<<56, 256, 0, stream>>>(w_in1, w_in2, w_e1, w_e2, w_n1, w_n2, wt);
    conv_x<<<1024, 256, 0, stream>>>(x, xb, 262144);

    dim3 gs(128, 4);
    gemm64<2><<<gs, 256, 0, stream>>>(xb, wt + 0 * 65536, b_in1, t1, 256, 99);
    gemm64<2><<<gs, 256, 0, stream>>>(t1, wt + 1 * 65536, b_in2, h, 256, 99);

    for (int p = 0; p < 2; p++) {
        // U' = h@We1_top + b_e1, V = h@We1_bot — one dispatch (split=4), bf16 out
        dim3 guv(128, 8);
        gemm64<4><<<guv, 256, 0, stream>>>(h, wt + 2 * 65536, b_e1, UVb, 512, 4);
        edge_fused<<<512, 512, 0, stream>>>(UVb, wt + 4 * 65536, b_e2, ag);
        gemm64<2><<<gs, 256, 0, stream>>>(ag, wt + 5 * 65536, b_n1, t1, 256, 99);
        if (p == 0)
            gemm64<2><<<gs, 256, 0, stream>>>(t1, wt + 6 * 65536, b_n2, h, 256, 99);
        else
            gemm64<3><<<gs, 256, 0, stream>>>(t1, wt + 6 * 65536, b_n2, (float*)d_out, 256, 99);
    }
}

// Round 6
// 146.410 us; speedup vs baseline: 1.2131x; 1.1414x over previous
//
#include <hip/hip_runtime.h>

// GNN encoder, B=256, N=32, F=256, fully-connected edges, 2 passes.
// bf16 MFMA 16x16x32, fp32 accum.
// edge_fused v7: 4-wave blocks (2 independent blocks/CU), wave tile 128x64,
// B-frags streamed from L2 (swizzled weight image) into registers per k-step,
// A (= relu(U'+V)) built on the fly into a 1-barrier LDS double buffer.

typedef short bf16x8 __attribute__((ext_vector_type(8)));
typedef float f32x4 __attribute__((ext_vector_type(4)));
typedef unsigned short ushort_t;

__device__ __forceinline__ unsigned short f2bf(float f) {
    unsigned u = __float_as_uint(f);
    u += 0x7fff + ((u >> 16) & 1);   // RNE
    return (unsigned short)(u >> 16);
}
__device__ __forceinline__ float lo16f(unsigned w) { return __uint_as_float(w << 16); }
__device__ __forceinline__ float hi16f(unsigned w) { return __uint_as_float(w & 0xffff0000u); }
__device__ __forceinline__ unsigned cvt_pk_bf16(float lo, float hi) {
    unsigned r;
    asm volatile("v_cvt_pk_bf16_f32 %0, %1, %2" : "=v"(r) : "v"(lo), "v"(hi));
    return r;
}
__device__ __forceinline__ void gload16(const void* g, void* l) {
    __builtin_amdgcn_global_load_lds(
        (const __attribute__((address_space(1))) void*)g,
        (__attribute__((address_space(3))) void*)l, 16, 0, 0);
}

// ---------------------------------------------------------------------------
// Weight prep: logical Wt[n][k] -> swizzled LDS image:
// idx = kb*8192 + n*32 + (kc ^ ((n>>1)&3))*8 + (k&7), kb = k>>5, kc = (k>>3)&3.
__global__ __launch_bounds__(256) void prep_weights(
    const float* __restrict__ w_in1, const float* __restrict__ w_in2,
    const float* __restrict__ w_e1,  const float* __restrict__ w_e2,
    const float* __restrict__ w_n1,  const float* __restrict__ w_n2,
    ushort_t* __restrict__ dst)
{
    __shared__ ushort_t tile[32][264];
    const int wid = blockIdx.x >> 3;   // 0..6
    const int kb  = blockIdx.x & 7;
    const float* src;
    switch (wid) {
        case 0: src = w_in1; break;
        case 1: src = w_in2; break;
        case 2: src = w_e1; break;              // top half (send side)
        case 3: src = w_e1 + 65536; break;      // bottom half (recv side)
        case 4: src = w_e2; break;
        case 5: src = w_n1; break;
        default: src = w_n2; break;
    }
    const int t = threadIdx.x;
#pragma unroll
    for (int k0 = 0; k0 < 32; k0++)
        tile[k0][t] = f2bf(src[(size_t)(kb * 32 + k0) * 256 + t]);  // coalesced
    __syncthreads();
    ushort_t* base = dst + wid * 65536 + kb * 8192 + t * 32;
    const int sw = (t >> 1) & 3;
#pragma unroll
    for (int kc = 0; kc < 4; kc++) {
        union { uint4 q; ushort_t u[8]; } w;
#pragma unroll
        for (int ko = 0; ko < 8; ko++) w.u[ko] = tile[kc * 8 + ko][t];
        *(uint4*)&base[(kc ^ sw) * 8] = w.q;
    }
}

// x fp32 -> bf16
__global__ __launch_bounds__(256) void conv_x(
    const float* __restrict__ x, ushort_t* __restrict__ xb, int n8)
{
    int i = blockIdx.x * 256 + threadIdx.x;
    if (i >= n8) return;
    const float4* p = (const float4*)x + (size_t)i * 2;
    float4 a = p[0], b = p[1];
    ushort4 o0 = make_ushort4(f2bf(a.x), f2bf(a.y), f2bf(a.z), f2bf(a.w));
    ushort4 o1 = make_ushort4(f2bf(b.x), f2bf(b.y), f2bf(b.z), f2bf(b.w));
    ((ushort4*)xb)[(size_t)i * 2]     = o0;
    ((ushort4*)xb)[(size_t)i * 2 + 1] = o1;
}

// ---------------------------------------------------------------------------
// Direct GEMM. Tile 64x64, 4 waves (2x2), gload_lds staging, 1-barrier dbuf.
// split: blockIdx.y >= split -> second weight image (WB+65536), null bias,
// output cols offset 256 (merged U'/V dispatch).
// EPI: 2 bias+relu bf16, 3 bias+relu f32, 4 bias(optional)+no-relu bf16
template <int EPI>
__global__ __launch_bounds__(256) void gemm64(
    const ushort_t* __restrict__ A, const ushort_t* __restrict__ WB,
    const float* __restrict__ bias, void* __restrict__ out, int ldc, int split)
{
    __shared__ ushort_t As[2][2048];
    __shared__ ushort_t Bs[2][2048];

    const int mb = (blockIdx.x & 7) * 16 + (blockIdx.x >> 3);  // XCD swizzle
    const int m0 = mb * 64;
    const int ny = blockIdx.y;
    int nloc; const ushort_t* wb; const float* bp; int nout;
    if (ny >= split) { nloc = (ny - split) * 64; wb = WB + 65536; bp = nullptr; nout = 256 + nloc; }
    else             { nloc = ny * 64;           wb = WB;         bp = bias;    nout = nloc; }

    const int t = threadIdx.x;
    const int lane = t & 63;
    const int w = t >> 6;
    const int wm = w >> 1, wn = w & 1;
    const int lr = lane & 15, lg = lane >> 4;

    const int arow = w * 16 + (lane >> 2);
    const int ac = (lane & 3) ^ ((arow >> 1) & 3);
    const ushort_t* asrc = A + (size_t)(m0 + arow) * 256 + ac * 8;
    const ushort_t* bsrc = wb + nloc * 32 + w * 512 + lane * 8;

    int aoff[2], boff[2];
#pragma unroll
    for (int f = 0; f < 2; f++) {
        int r = wm * 32 + f * 16 + lr;
        aoff[f] = r * 32 + ((lg ^ ((r >> 1) & 3)) * 8);
        int rb = wn * 32 + f * 16 + lr;
        boff[f] = rb * 32 + ((lg ^ ((rb >> 1) & 3)) * 8);
    }

    f32x4 acc[2][2] = {};

    gload16(asrc, &As[0][w * 512]);
    gload16(bsrc, &Bs[0][w * 512]);

    for (int kb = 1; kb < 8; kb++) {
        __syncthreads();
        gload16(asrc + kb * 32,   &As[kb & 1][w * 512]);
        gload16(bsrc + kb * 8192, &Bs[kb & 1][w * 512]);
        const int cur = (kb - 1) & 1;
        bf16x8 a0 = *(const bf16x8*)&As[cur][aoff[0]];
        bf16x8 a1 = *(const bf16x8*)&As[cur][aoff[1]];
        bf16x8 b0 = *(const bf16x8*)&Bs[cur][boff[0]];
        bf16x8 b1 = *(const bf16x8*)&Bs[cur][boff[1]];
        acc[0][0] = __builtin_amdgcn_mfma_f32_16x16x32_bf16(a0, b0, acc[0][0], 0, 0, 0);
        acc[0][1] = __builtin_amdgcn_mfma_f32_16x16x32_bf16(a0, b1, acc[0][1], 0, 0, 0);
        acc[1][0] = __builtin_amdgcn_mfma_f32_16x16x32_bf16(a1, b0, acc[1][0], 0, 0, 0);
        acc[1][1] = __builtin_amdgcn_mfma_f32_16x16x32_bf16(a1, b1, acc[1][1], 0, 0, 0);
    }
    __syncthreads();
    {
        bf16x8 a0 = *(const bf16x8*)&As[1][aoff[0]];
        bf16x8 a1 = *(const bf16x8*)&As[1][aoff[1]];
        bf16x8 b0 = *(const bf16x8*)&Bs[1][boff[0]];
        bf16x8 b1 = *(const bf16x8*)&Bs[1][boff[1]];
        acc[0][0] = __builtin_amdgcn_mfma_f32_16x16x32_bf16(a0, b0, acc[0][0], 0, 0, 0);
        acc[0][1] = __builtin_amdgcn_mfma_f32_16x16x32_bf16(a0, b1, acc[0][1], 0, 0, 0);
        acc[1][0] = __builtin_amdgcn_mfma_f32_16x16x32_bf16(a1, b0, acc[1][0], 0, 0, 0);
        acc[1][1] = __builtin_amdgcn_mfma_f32_16x16x32_bf16(a1, b1, acc[1][1], 0, 0, 0);
    }

#pragma unroll
    for (int fm = 0; fm < 2; fm++)
#pragma unroll
        for (int fn = 0; fn < 2; fn++) {
            const int cl = wn * 32 + fn * 16 + lr;
            float bv = 0.f;
            if (bp) bv = bp[nloc + cl];
#pragma unroll
            for (int r = 0; r < 4; r++) {
                const int row = m0 + wm * 32 + fm * 16 + lg * 4 + r;
                float v = acc[fm][fn][r] + bv;
                if constexpr (EPI == 2 || EPI == 3) v = fmaxf(v, 0.f);
                if constexpr (EPI == 3)
                    ((float*)out)[(size_t)row * ldc + nout + cl] = v;
                else
                    ((ushort_t*)out)[(size_t)row * ldc + nout + cl] = f2bf(v);
            }
        }
}

// ---------------------------------------------------------------------------
// Fused edge layer-2 + scatter-mean, v7.
// Grid 2048 x 256 thr (4 waves). Block = (batch, quad of 4 receivers):
// 128 virtual rows (4 recv x 32 slots, slot31 dummy) x N=256.
// Wave w owns cols [w*64, w*64+64): wave tile 128x64, acc[8][4].
// A = relu(U'[send]+V[recv]) built into 1-barrier LDS dbuf (only LDS user).
// B-frags loaded per k-step from the swizzled L2-resident w_e2 image,
// prefetched one step ahead.
__global__ __launch_bounds__(256, 2) void edge_fused(
    const ushort_t* __restrict__ UVb,   // [8192][512] bf16: U'(+b_e1) | V
    const ushort_t* __restrict__ WBsw,  // swizzled w_e2 image
    const float* __restrict__ b2,
    ushort_t* __restrict__ agg)         // [8192][256] bf16
{
    __shared__ ushort_t As[2][4096];    // 128 rows x 32 k each

    const int logical = (blockIdx.x & 7) * 256 + (blockIdx.x >> 3);  // 2048%8==0
    const int bb = logical >> 3;        // batch
    const int g0 = (logical & 7) * 4;   // first receiver of the quad
    const int t = threadIdx.x;
    const int lane = t & 63;
    const int w = t >> 6;
    const int lr = lane & 15, lg = lane >> 4;

    // ---- A-build mapping: thread -> (row, k-half). 2 threads per row.
    const int brow = t >> 1;            // 0..127
    const int kh = t & 1;               // which 16-k half
    const int jr = brow >> 5;           // receiver within quad
    const int s = brow & 31;            // slot
    const int j = g0 + jr;
    const int si = (s == 31) ? j : (s + (s >= j ? 1 : 0));
    const ushort_t* up = UVb + (size_t)(bb * 32 + si) * 512 + kh * 16;
    const ushort_t* vp = UVb + (size_t)(bb * 32 + j) * 512 + 256 + kh * 16;
    const int swz = (brow >> 1) & 3;
    const int aw0 = brow * 32 + (((kh * 2)     ^ swz) * 8);
    const int aw1 = brow * 32 + (((kh * 2 + 1) ^ swz) * 8);

    // ---- MFMA-side offsets
    int aoff[8];
#pragma unroll
    for (int m = 0; m < 8; m++) {
        const int r = m * 16 + lr;
        aoff[m] = r * 32 + ((lg ^ ((r >> 1) & 3)) * 8);
    }
    int boff[4];
#pragma unroll
    for (int fn = 0; fn < 4; fn++) {
        const int n = w * 64 + fn * 16 + lr;
        boff[fn] = n * 32 + ((lg ^ ((n >> 1) & 3)) * 8);
    }

    // ---- prologue: build k-tile 0, load B k-tile 0
    {
        uint4 ua = *(const uint4*)up,        ub = *(const uint4*)(up + 8);
        uint4 va = *(const uint4*)vp,        vb = *(const uint4*)(vp + 8);
        uint4 q0, q1;
        q0.x = cvt_pk_bf16(fmaxf(lo16f(ua.x) + lo16f(va.x), 0.f), fmaxf(hi16f(ua.x) + hi16f(va.x), 0.f));
        q0.y = cvt_pk_bf16(fmaxf(lo16f(ua.y) + lo16f(va.y), 0.f), fmaxf(hi16f(ua.y) + hi16f(va.y), 0.f));
        q0.z = cvt_pk_bf16(fmaxf(lo16f(ua.z) + lo16f(va.z), 0.f), fmaxf(hi16f(ua.z) + hi16f(va.z), 0.f));
        q0.w = cvt_pk_bf16(fmaxf(lo16f(ua.w) + lo16f(va.w), 0.f), fmaxf(hi16f(ua.w) + hi16f(va.w), 0.f));
        q1.x = cvt_pk_bf16(fmaxf(lo16f(ub.x) + lo16f(vb.x), 0.f), fmaxf(hi16f(ub.x) + hi16f(vb.x), 0.f));
        q1.y = cvt_pk_bf16(fmaxf(lo16f(ub.y) + lo16f(vb.y), 0.f), fmaxf(hi16f(ub.y) + hi16f(vb.y), 0.f));
        q1.z = cvt_pk_bf16(fmaxf(lo16f(ub.z) + lo16f(vb.z), 0.f), fmaxf(hi16f(ub.z) + hi16f(vb.z), 0.f));
        q1.w = cvt_pk_bf16(fmaxf(lo16f(ub.w) + lo16f(vb.w), 0.f), fmaxf(hi16f(ub.w) + hi16f(vb.w), 0.f));
        *(uint4*)&As[0][aw0] = q0;
        *(uint4*)&As[0][aw1] = q1;
    }
    bf16x8 bc[4];
#pragma unroll
    for (int fn = 0; fn < 4; fn++) bc[fn] = *(const bf16x8*)&WBsw[boff[fn]];

    f32x4 acc[8][4] = {};

#pragma unroll
    for (int kb = 0; kb < 8; kb++) {
        __syncthreads();                      // As[kb&1] ready
        // prefetch next-step inputs (hidden under this step's MFMAs)
        uint4 ua, ub, va, vb;
        bf16x8 bn[4];
        if (kb < 7) {
            const ushort_t* upn = up + (kb + 1) * 32;
            const ushort_t* vpn = vp + (kb + 1) * 32;
            ua = *(const uint4*)upn;  ub = *(const uint4*)(upn + 8);
            va = *(const uint4*)vpn;  vb = *(const uint4*)(vpn + 8);
#pragma unroll
            for (int fn = 0; fn < 4; fn++)
                bn[fn] = *(const bf16x8*)&WBsw[(kb + 1) * 8192 + boff[fn]];
        }
        // MFMA on current tile
        bf16x8 af[8];
#pragma unroll
        for (int m = 0; m < 8; m++) af[m] = *(const bf16x8*)&As[kb & 1][aoff[m]];
#pragma unroll
        for (int fn = 0; fn < 4; fn++)
#pragma unroll
            for (int m = 0; m < 8; m++)
                acc[m][fn] = __builtin_amdgcn_mfma_f32_16x16x32_bf16(
                    af[m], bc[fn], acc[m][fn], 0, 0, 0);
        // build next tile + rotate B
        if (kb < 7) {
            uint4 q0, q1;
            q0.x = cvt_pk_bf16(fmaxf(lo16f(ua.x) + lo16f(va.x), 0.f), fmaxf(hi16f(ua.x) + hi16f(va.x), 0.f));
            q0.y = cvt_pk_bf16(fmaxf(lo16f(ua.y) + lo16f(va.y), 0.f), fmaxf(hi16f(ua.y) + hi16f(va.y), 0.f));
            q0.z = cvt_pk_bf16(fmaxf(lo16f(ua.z) + lo16f(va.z), 0.f), fmaxf(hi16f(ua.z) + hi16f(va.z), 0.f));
            q0.w = cvt_pk_bf16(fmaxf(lo16f(ua.w) + lo16f(va.w), 0.f), fmaxf(hi16f(ua.w) + hi16f(va.w), 0.f));
            q1.x = cvt_pk_bf16(fmaxf(lo16f(ub.x) + lo16f(vb.x), 0.f), fmaxf(hi16f(ub.x) + hi16f(vb.x), 0.f));
            q1.y = cvt_pk_bf16(fmaxf(lo16f(ub.y) + lo16f(vb.y), 0.f), fmaxf(hi16f(ub.y) + hi16f(vb.y), 0.f));
            q1.z = cvt_pk_bf16(fmaxf(lo16f(ub.z) + lo16f(vb.z), 0.f), fmaxf(hi16f(ub.z) + hi16f(vb.z), 0.f));
            q1.w = cvt_pk_bf16(fmaxf(lo16f(ub.w) + lo16f(vb.w), 0.f), fmaxf(hi16f(ub.w) + hi16f(vb.w), 0.f));
            *(uint4*)&As[(kb + 1) & 1][aw0] = q0;
            *(uint4*)&As[(kb + 1) & 1][aw1] = q1;
#pragma unroll
            for (int fn = 0; fn < 4; fn++) bc[fn] = bn[fn];
        }
    }

    // ---- Epilogue: bias+relu, sum 31 real slots per receiver, /31, write bf16.
#pragma unroll
    for (int fn = 0; fn < 4; fn++) {
        const int col = w * 64 + fn * 16 + lr;
        const float bvf = b2[col];
#pragma unroll
        for (int recv = 0; recv < 4; recv++) {
            float sum = 0.f;
#pragma unroll
            for (int q = 0; q < 2; q++) {
                const int fm = recv * 2 + q;
#pragma unroll
                for (int r = 0; r < 4; r++) {
                    float v = fmaxf(acc[fm][fn][r] + bvf, 0.f);
                    if (!(q == 1 && lg == 3 && r == 3)) sum += v;  // skip slot 31
                }
            }
            sum += __shfl_xor(sum, 16);
            sum += __shfl_xor(sum, 32);
            if (lane < 16)
                agg[(size_t)(bb * 32 + g0 + recv) * 256 + col] = f2bf(sum * (1.0f / 31.0f));
        }
    }
}

// ---------------------------------------------------------------------------
extern "C" void kernel_launch(void* const* d_in, const int* in_sizes, int n_in,
                              void* d_out, int out_size, void* d_ws, size_t ws_size,
                              hipStream_t stream)
{
    const float* x     = (const float*)d_in[0];
    const float* w_in1 = (const float*)d_in[3];
    const float* b_in1 = (const float*)d_in[4];
    const float* w_in2 = (const float*)d_in[5];
    const float* b_in2 = (const float*)d_in[6];
    const float* w_e1  = (const float*)d_in[7];
    const float* b_e1  = (const float*)d_in[8];
    const float* w_e2  = (const float*)d_in[9];
    const float* b_e2  = (const float*)d_in[10];
    const float* w_n1  = (const float*)d_in[11];
    const float* b_n1  = (const float*)d_in[12];
    const float* w_n2  = (const float*)d_in[13];
    const float* b_n2  = (const float*)d_in[14];

    char* ws = (char*)d_ws;
    size_t off = 0;
    auto alloc = [&](size_t n) { char* p = ws + off; off += (n + 255) & ~(size_t)255; return p; };

    ushort_t* wt  = (ushort_t*)alloc(7 * 65536 * sizeof(ushort_t));
    ushort_t* xb  = (ushort_t*)alloc(8192 * 256 * 2);
    ushort_t* h   = (ushort_t*)alloc(8192 * 256 * 2);
    ushort_t* t1  = (ushort_t*)alloc(8192 * 256 * 2);
    ushort_t* UVb = (ushort_t*)alloc(8192 * 512 * 2);
    ushort_t* ag  = (ushort_t*)alloc(8192 * 256 * 2);
    (void)ws_size; (void)in_sizes; (void)n_in; (void)out_size;

    prep_weights<<<56, 256, 0, stream>>>(w_in1, w_in2, w_e1, w_e2, w_n1, w_n2, wt);
    conv_x<<<1024, 256, 0, stream>>>(x, xb, 262144);

    dim3 gs(128, 4);
    gemm64<2><<<gs, 256, 0, stream>>>(xb, wt + 0 * 65536, b_in1, t1, 256, 99);
    gemm64<2><<<gs, 256, 0, stream>>>(t1, wt + 1 * 65536, b_in2, h, 256, 99);

    for (int p = 0; p < 2; p++) {
        // U' = h@We1_top + b_e1, V = h@We1_bot — one dispatch (split=4), bf16 out
        dim3 guv(128, 8);
        gemm64<4><<<guv, 256, 0, stream>>>(h, wt + 2 * 65536, b_e1, UVb, 512, 4);
        edge_fused<<<2048, 256, 0, stream>>>(UVb, wt + 4 * 65536, b_e2, ag);
        gemm64<2><<<gs, 256, 0, stream>>>(ag, wt + 5 * 65536, b_n1, t1, 256, 99);
        if (p == 0)
            gemm64<2><<<gs, 256, 0, stream>>>(t1, wt + 6 * 65536, b_n2, h, 256, 99);
        else
            gemm64<3><<<gs, 256, 0, stream>>>(t1, wt + 6 * 65536, b_n2, (float*)d_out, 256, 99);
    }
}